// Round 19
// baseline (752.760 us; speedup 1.0000x reference)
//
#include <hip/hip_runtime.h>
#include <hip/hip_bf16.h>

// ---------------- problem constants ----------------
#define T_TOK 4096
#define HD    2048
#define NE    64
#define TOPK  8
#define IMID  512
#define N13   1024                 // 2*I
#define NPAIR (T_TOK*TOPK)         // 32768
#define NROWS (NPAIR + T_TOK)      // 36864
#define MAXT1 352                  // 128-row tiles
#define CVTY  32                   // extra grid rows in gemm1 for w2 conversion (8*32=256 blocks)
#define RSCALE 2.5f
#define W2ELEMS  ((size_t)NE * IMID * HD)   // 67,108,864
#define SW2ELEMS ((size_t)IMID * HD)        //  1,048,576

typedef __attribute__((ext_vector_type(8)))  __bf16 bf16x8;
typedef __attribute__((ext_vector_type(4)))  __bf16 bf16x4;
typedef __attribute__((ext_vector_type(4)))  float  f32x4;

// NOTE (hard-won): __launch_bounds__ 2nd arg on this hipcc = min BLOCKS/CU.
// (512,4) caps VGPR at 64 -> catastrophic spill (R13). Use (512,2) = 128 VGPRs.

// ---------------- init: counters only ----------------
__global__ void init_small(int* __restrict__ counts, int* __restrict__ curs) {
  int tid = threadIdx.x;
  if (tid < NE + 1) { counts[tid] = 0; curs[tid] = 0; }
}
__global__ __launch_bounds__(256) void zero_out_kernel(float4* __restrict__ out4) {
  out4[blockIdx.x * 256 + threadIdx.x] = float4{0.f, 0.f, 0.f, 0.f};
}

// ---------------- router logits (16 tokens/block) + fused hidden->bf16 ----------------
__global__ __launch_bounds__(256) void logits_kernel(const float* __restrict__ hs,
                                                     const float* __restrict__ gw,
                                                     float* __restrict__ logits,
                                                     __bf16* __restrict__ hidden_bf) {
  __shared__ float hsm[64][16];
  __shared__ float gwm[64][64];
  int tid = threadIdx.x;
  int tb = blockIdx.x * 16;
  int tok = tid >> 4, e4 = (tid & 15) * 4;
  float acc[4] = {0.f, 0.f, 0.f, 0.f};
  for (int c = 0; c < 32; ++c) {
    int kb = c * 64;
    {
      int t16 = tid & 15, kq = tid >> 4;
      float4 f = *(const float4*)&hs[(size_t)(tb + t16) * HD + kb + kq * 4];
      hsm[kq * 4 + 0][t16] = f.x; hsm[kq * 4 + 1][t16] = f.y;
      hsm[kq * 4 + 2][t16] = f.z; hsm[kq * 4 + 3][t16] = f.w;
      bf16x4 hv = { (__bf16)f.x, (__bf16)f.y, (__bf16)f.z, (__bf16)f.w };
      *(bf16x4*)&hidden_bf[(size_t)(tb + t16) * HD + kb + kq * 4] = hv;
#pragma unroll
      for (int it = 0; it < 4; ++it) {
        int q = tid + it * 256;
        int gr = q >> 4, gc = (q & 15) * 4;
        *(float4*)&gwm[gr][gc] = *(const float4*)&gw[(size_t)(kb + gr) * NE + gc];
      }
    }
    __syncthreads();
#pragma unroll 8
    for (int k = 0; k < 64; ++k) {
      float h = hsm[k][tok];
      float4 g = *(const float4*)&gwm[k][e4];
      acc[0] += h * g.x; acc[1] += h * g.y; acc[2] += h * g.z; acc[3] += h * g.w;
    }
    __syncthreads();
  }
#pragma unroll
  for (int j = 0; j < 4; ++j) logits[(size_t)(tb + tok) * NE + e4 + j] = acc[j];
}

// ---------------- sigmoid + top-8 ----------------
__global__ __launch_bounds__(256) void top8_kernel(const float* __restrict__ logits,
                                                   int* __restrict__ topk_id,
                                                   float* __restrict__ pair_w,
                                                   int* __restrict__ counts) {
  int lane = threadIdx.x & 63;
  int t = blockIdx.x * 4 + (threadIdx.x >> 6);
  float v = logits[(size_t)t * NE + lane];
  float s = 1.f / (1.f + __expf(-v));
  float cur = s, ssum = 0.f;
  int myid = 0; float myw = 0.f;
  for (int k = 0; k < TOPK; ++k) {
    float bv = cur; int bi = lane;
#pragma unroll
    for (int off = 32; off >= 1; off >>= 1) {
      float ov = __shfl_xor(bv, off);
      int   oi = __shfl_xor(bi, off);
      if (ov > bv || (ov == bv && oi < bi)) { bv = ov; bi = oi; }
    }
    ssum += bv;
    if (lane == k) { myid = bi; myw = bv; }
    if (lane == bi) cur = -1.f;
  }
  if (lane < TOPK) {
    topk_id[(size_t)t * TOPK + lane] = myid;
    pair_w[(size_t)t * TOPK + lane] = myw / ssum * RSCALE;
    atomicAdd(&counts[myid], 1);
  }
}

// ---------------- scan: LDS-resident, 128-row tiles ----------------
__global__ void scan_kernel(const int* __restrict__ counts, int* __restrict__ offs,
                            int2* __restrict__ tiles) {
  __shared__ int cnt[65], pref[66], tp[66];
  int tid = threadIdx.x;                     // 128 threads
  if (tid < 64) cnt[tid] = counts[tid];
  if (tid == 64) cnt[64] = T_TOK;
  __syncthreads();
  if (tid == 0) {
    int o = 0, t = 0;
    for (int e = 0; e <= 64; ++e) {
      pref[e] = o; tp[e] = t;
      o += cnt[e]; t += (cnt[e] + 127) >> 7;
    }
    pref[65] = o; tp[65] = t;
  }
  __syncthreads();
  if (tid <= 64) {
    offs[tid] = pref[tid];
    int c = cnt[tid], base = pref[tid], tb = tp[tid];
    int nt = (c + 127) >> 7;
    for (int i = 0; i < nt; ++i) {
      int rr = c - i * 128; if (rr > 128) rr = 128;
      tiles[tb + i] = make_int2(base + i * 128, (tid << 16) | rr);
    }
  }
  __syncthreads();
  for (int i = tp[65] + tid; i < MAXT1; i += 128) tiles[i] = make_int2(0, 0);
}

// ---------------- scatter (+ inverse map for combine) ----------------
__global__ __launch_bounds__(256) void scatter_kernel(const int* __restrict__ topk_id,
                                                      const float* __restrict__ pair_w,
                                                      const int* __restrict__ offs,
                                                      int* __restrict__ curs,
                                                      int* __restrict__ row_token,
                                                      float* __restrict__ row_w,
                                                      int* __restrict__ inv8) {
  int p = blockIdx.x * 256 + threadIdx.x;
  int dst, t; float w;
  if (p < NPAIR) {
    t = p >> 3; int e = topk_id[p]; w = pair_w[p];
    dst = offs[e] + atomicAdd(&curs[e], 1);
    inv8[p] = dst;
  } else {
    t = p - NPAIR; w = 1.0f;
    dst = NPAIR + t;
  }
  row_token[dst] = t;
  row_w[dst] = w;
}

// ---------------- helpers ----------------
__device__ __forceinline__ int swz(int row, int kbyte) {     // [row][64 bf16 = 128B]
  return row * 128 + (kbyte ^ ((row & 7) << 4));
}
__device__ __forceinline__ void glds16(const void* g, void* l) {
  __builtin_amdgcn_global_load_lds((const __attribute__((address_space(1))) void*)g,
                                   (__attribute__((address_space(3))) void*)l, 16, 0, 0);
}
// 8 elems (fp32 or bf16) -> one swizzled bf16x8 LDS write
__device__ __forceinline__ void store_bx8(__bf16* Bs, int col, int kbyte, const float* p) {
  bf16x8 v = { (__bf16)p[0], (__bf16)p[1], (__bf16)p[2], (__bf16)p[3],
               (__bf16)p[4], (__bf16)p[5], (__bf16)p[6], (__bf16)p[7] };
  *(bf16x8*)&Bs[swz(col, kbyte) >> 1] = v;
}
__device__ __forceinline__ void store_bx8(__bf16* Bs, int col, int kbyte, const __bf16* p) {
  bf16x8 v = { p[0], p[1], p[2], p[3], p[4], p[5], p[6], p[7] };
  *(bf16x8*)&Bs[swz(col, kbyte) >> 1] = v;
}

// ======= grouped GEMM1: 512 thr, BM=128, BN=64g+64u (nsplit 8), BK=64 ==================
// R11-proven pipeline (355 us, conflicts=0). DOCVT=1 appends 256 converter blocks
// (blockIdx.y >= MAXT1) that stream w2+sw2 -> bf16 into ws using gemm1's idle HBM BW
// (gemm1 runs at only 28% of peak). Kernel boundary orders the writes before gemm2.
#define G1STEP(S, Acur, Anx2, BGc, BUc, BGn, BUn, RL, RS)                                  \
  {                                                                                        \
    if ((S) + 2 < 32) {                                                                    \
      const float* Bn_ = Bp0 + (size_t)((S) + 2) * 64 * N13;                               \
      _Pragma("unroll") for (int r = 0; r < 16; ++r) RL[r] = Bn_[(size_t)r * N13];         \
      __builtin_amdgcn_sched_barrier(0);                                                   \
      _Pragma("unroll") for (int i = 0; i < 2; ++i)                                        \
        glds16(Abase[i] + ((S) + 2) * 64, (Anx2) + wv * 1024 + i * 512);                   \
    }                                                                                      \
    __builtin_amdgcn_sched_barrier(0);                                                     \
    __builtin_amdgcn_s_setprio(1);                                                         \
    _Pragma("unroll") for (int kk = 0; kk < 2; ++kk) {                                     \
      int koff = kk * 64 + lq * 16;                                                        \
      bf16x8 a[2], bg[2], bu[2];                                                           \
      _Pragma("unroll") for (int i = 0; i < 2; ++i)                                        \
        a[i] = *(const bf16x8*)&(Acur)[swz(wrow * 32 + i * 16 + l15, koff) >> 1];          \
      _Pragma("unroll") for (int j = 0; j < 2; ++j) {                                      \
        bg[j] = *(const bf16x8*)&(BGc)[swz(wc * 32 + j * 16 + l15, koff) >> 1];            \
        bu[j] = *(const bf16x8*)&(BUc)[swz(wc * 32 + j * 16 + l15, koff) >> 1];            \
      }                                                                                    \
      _Pragma("unroll") for (int i = 0; i < 2; ++i)                                        \
        _Pragma("unroll") for (int j = 0; j < 2; ++j) {                                    \
          accg[i][j] = __builtin_amdgcn_mfma_f32_16x16x32_bf16(a[i], bg[j], accg[i][j], 0, 0, 0); \
          accu[i][j] = __builtin_amdgcn_mfma_f32_16x16x32_bf16(a[i], bu[j], accu[i][j], 0, 0, 0); \
        }                                                                                  \
    }                                                                                      \
    __builtin_amdgcn_s_setprio(0);                                                         \
    if ((S) + 1 < 32) {                                                                    \
      __bf16* Bmy_ = bm ? (BUn) : (BGn);                                                   \
      store_bx8(Bmy_, bcol, bkq * 32, RS);                                                 \
      store_bx8(Bmy_, bcol, bkq * 32 + 16, RS + 8);                                        \
    }                                                                                      \
    if ((S) + 2 < 32) asm volatile("s_waitcnt vmcnt(18) lgkmcnt(0)" ::: "memory");         \
    else              asm volatile("s_waitcnt vmcnt(0) lgkmcnt(0)"  ::: "memory");         \
    __builtin_amdgcn_s_barrier();                                                          \
    __builtin_amdgcn_sched_barrier(0);                                                     \
  }

template<int DOCVT>
__global__ __launch_bounds__(512, 2) void gemm1_kernel(const __bf16* __restrict__ hidden_bf,
                                                       const float* __restrict__ w13,
                                                       const float* __restrict__ sw13,
                                                       const int* __restrict__ row_token,
                                                       const int2* __restrict__ tiles,
                                                       __bf16* __restrict__ hbuf,
                                                       const float* __restrict__ w2f,
                                                       const float* __restrict__ sw2f,
                                                       __bf16* __restrict__ wdst) {
  if (DOCVT && blockIdx.y >= MAXT1) {
    // converter role: grid-stride fp32->bf16 of w2 then sw2 (8-elem chunks, no straddle)
    int cb = (blockIdx.y - MAXT1) * 8 + blockIdx.x;            // 0..255
    const size_t NV = (W2ELEMS + SW2ELEMS) / 8;
    for (size_t v = (size_t)cb * 512 + threadIdx.x; v < NV; v += (size_t)256 * 512) {
      size_t base = v * 8;
      const float* src = (base < W2ELEMS) ? (w2f + base) : (sw2f + (base - W2ELEMS));
      float4 a = *(const float4*)src, b = *(const float4*)(src + 4);
      bf16x8 o = { (__bf16)a.x, (__bf16)a.y, (__bf16)a.z, (__bf16)a.w,
                   (__bf16)b.x, (__bf16)b.y, (__bf16)b.z, (__bf16)b.w };
      *(bf16x8*)(wdst + base) = o;
    }
    return;
  }
  int2 td = tiles[blockIdx.y];
  int rows = td.y & 0xFFFF;
  if (rows == 0) return;
  int e = td.y >> 16, row0 = td.x;
  const float* W = (e < NE) ? (w13 + (size_t)e * (HD * N13)) : sw13;  // [2048][1024]
  int n0 = blockIdx.x * 64;                                           // gate cols; up +512

  __shared__ __bf16 As0[128 * 64], As1[128 * 64], As2[128 * 64];  // 3 x 16 KB
  __shared__ __bf16 Bgs[2][64 * 64];                // 16 KB
  __shared__ __bf16 Bus[2][64 * 64];                // 16 KB   -> 80 KB total

  int tid = threadIdx.x;
  int lane = tid & 63, wv = tid >> 6;          // 8 waves
  int wrow = wv >> 1, wc = wv & 1;             // rows [wrow*32,+32), col-half wc
  int l15 = lane & 15, lq = lane >> 4;

  int kswz = (((lane & 7) ^ ((lane >> 3) & 7)) << 3);
  const __bf16* Abase[2];
#pragma unroll
  for (int i = 0; i < 2; ++i) {
    int grow = row0 + wv * 16 + i * 8 + (lane >> 3);
    if (grow >= NROWS) grow = NROWS - 1;
    Abase[i] = hidden_bf + (size_t)row_token[grow] * HD + kswz;
  }
  int bm = tid >> 8, bcol = tid & 63, bkq = (tid >> 6) & 3;
  const float* Bp0 = W + (size_t)(bkq * 16) * N13 + (bm ? 512 + n0 : n0) + bcol;

  // ---- prologue: B(0)->pA, glds A(0)->As0; B(1)->pB, glds A(1)->As1; store B(0) ----
  float pA[16], pB[16];
#pragma unroll
  for (int r = 0; r < 16; ++r) pA[r] = Bp0[(size_t)r * N13];
  __builtin_amdgcn_sched_barrier(0);
#pragma unroll
  for (int i = 0; i < 2; ++i) glds16(Abase[i], As0 + wv * 1024 + i * 512);
  __builtin_amdgcn_sched_barrier(0);
  {
    const float* B1 = Bp0 + (size_t)64 * N13;
#pragma unroll
    for (int r = 0; r < 16; ++r) pB[r] = B1[(size_t)r * N13];
  }
  __builtin_amdgcn_sched_barrier(0);
#pragma unroll
  for (int i = 0; i < 2; ++i) glds16(Abase[i] + 64, As1 + wv * 1024 + i * 512);
  __builtin_amdgcn_sched_barrier(0);
  {
    __bf16* Bmy = bm ? Bus[0] : Bgs[0];
    store_bx8(Bmy, bcol, bkq * 32, pA);
    store_bx8(Bmy, bcol, bkq * 32 + 16, pA + 8);
  }
  asm volatile("s_waitcnt vmcnt(18) lgkmcnt(0)" ::: "memory");   // retires glds(0)
  __builtin_amdgcn_s_barrier();
  __builtin_amdgcn_sched_barrier(0);

  f32x4 accg[2][2], accu[2][2];
#pragma unroll
  for (int i = 0; i < 2; ++i)
#pragma unroll
    for (int j = 0; j < 2; ++j) { accg[i][j] = (f32x4)(0.f); accu[i][j] = (f32x4)(0.f); }

  __bf16 *Ac = As0, *A1 = As1, *A2 = As2;
  for (int s = 0; s < 32; s += 2) {
    G1STEP(s,     Ac, A2, Bgs[0], Bus[0], Bgs[1], Bus[1], pA, pB);
    { __bf16* t = Ac; Ac = A1; A1 = A2; A2 = t; }
    G1STEP(s + 1, Ac, A2, Bgs[1], Bus[1], Bgs[0], Bus[0], pB, pA);
    { __bf16* t = Ac; Ac = A1; A1 = A2; A2 = t; }
  }
  // epilogue: h = silu(g)*u
#pragma unroll
  for (int mi = 0; mi < 2; ++mi) {
#pragma unroll
    for (int r = 0; r < 4; ++r) {
      int rl = wrow * 32 + mi * 16 + lq * 4 + r;
      if (rl < rows) {
        size_t hrow = (size_t)(row0 + rl) * IMID;
#pragma unroll
        for (int j = 0; j < 2; ++j) {
          float g = accg[mi][j][r], u = accu[mi][j][r];
          float hv = g * u / (1.f + __expf(-g));
          hbuf[hrow + n0 + wc * 32 + j * 16 + l15] = (__bf16)hv;
        }
      }
    }
  }
}

// ======= grouped GEMM2: 512 thr, BM=128, BN=128 (nsplit 16), BK=64 =====================
// Same R11 pipeline; TB = bf16 (converted weights) or fp32 fallback.
#define G2STEP(S, Acur, Anx2, Bc, Bn, RL, RS)                                              \
  {                                                                                        \
    if ((S) + 2 < 8) {                                                                     \
      const TB* Bn_ = Bp0 + (size_t)((S) + 2) * 64 * HD;                                   \
      _Pragma("unroll") for (int r = 0; r < 16; ++r) RL[r] = Bn_[(size_t)r * HD];          \
      __builtin_amdgcn_sched_barrier(0);                                                   \
      _Pragma("unroll") for (int i = 0; i < 2; ++i)                                        \
        glds16(Abase[i] + ((S) + 2) * 64, (Anx2) + wv * 1024 + i * 512);                   \
    }                                                                                      \
    __builtin_amdgcn_sched_barrier(0);                                                     \
    __builtin_amdgcn_s_setprio(1);                                                         \
    _Pragma("unroll") for (int kk = 0; kk < 2; ++kk) {                                     \
      int koff = kk * 64 + lq * 16;                                                        \
      bf16x8 a[2], b[4];                                                                   \
      _Pragma("unroll") for (int i = 0; i < 2; ++i)                                        \
        a[i] = *(const bf16x8*)&(Acur)[swz(wrow * 32 + i * 16 + l15, koff) >> 1];          \
      _Pragma("unroll") for (int j = 0; j < 4; ++j)                                        \
        b[j] = *(const bf16x8*)&(Bc)[swz(wc * 64 + j * 16 + l15, koff) >> 1];              \
      _Pragma("unroll") for (int i = 0; i < 2; ++i)                                        \
        _Pragma("unroll") for (int j = 0; j < 4; ++j)                                      \
          acc[i][j] = __builtin_amdgcn_mfma_f32_16x16x32_bf16(a[i], b[j], acc[i][j], 0, 0, 0); \
    }                                                                                      \
    __builtin_amdgcn_s_setprio(0);                                                         \
    if ((S) + 1 < 8) {                                                                     \
      store_bx8((Bn), bcol, bkq * 32, RS);                                                 \
      store_bx8((Bn), bcol, bkq * 32 + 16, RS + 8);                                        \
    }                                                                                      \
    if ((S) + 2 < 8) asm volatile("s_waitcnt vmcnt(18) lgkmcnt(0)" ::: "memory");          \
    else             asm volatile("s_waitcnt vmcnt(0) lgkmcnt(0)"  ::: "memory");          \
    __builtin_amdgcn_s_barrier();                                                          \
    __builtin_amdgcn_sched_barrier(0);                                                     \
  }

template<typename TB, int MODE>
__global__ __launch_bounds__(512, 2) void gemm2_kernel(const __bf16* __restrict__ hbuf,
                                                       const TB* __restrict__ w2,
                                                       const TB* __restrict__ sw2,
                                                       const int* __restrict__ row_token,
                                                       const float* __restrict__ row_w,
                                                       const int2* __restrict__ tiles,
                                                       void* __restrict__ dstv) {
  int2 td = tiles[blockIdx.y];
  int rows = td.y & 0xFFFF;
  if (rows == 0) return;
  int e = td.y >> 16, row0 = td.x;
  const TB* W = (e < NE) ? (w2 + (size_t)e * (IMID * HD)) : sw2;      // [512][2048]
  int n0 = blockIdx.x * 128;

  __shared__ __bf16 As0[128 * 64], As1[128 * 64], As2[128 * 64];  // 3 x 16 KB
  __shared__ __bf16 Bs[2][128 * 64];                // 32 KB   -> 80 KB total

  int tid = threadIdx.x;
  int lane = tid & 63, wv = tid >> 6;
  int wrow = wv >> 1, wc = wv & 1;             // rows [wrow*32,+32), cols [wc*64,+64)
  int l15 = lane & 15, lq = lane >> 4;

  int kswz = (((lane & 7) ^ ((lane >> 3) & 7)) << 3);
  const __bf16* Abase[2];
#pragma unroll
  for (int i = 0; i < 2; ++i) {
    int grow = row0 + wv * 16 + i * 8 + (lane >> 3);
    if (grow >= NROWS) grow = NROWS - 1;
    Abase[i] = hbuf + (size_t)grow * IMID + kswz;
  }
  int bcol = tid & 127, bkq = tid >> 7;        // one col, 16 k-rows
  const TB* Bp0 = W + (size_t)(bkq * 16) * HD + n0 + bcol;

  TB pA[16], pB[16];
#pragma unroll
  for (int r = 0; r < 16; ++r) pA[r] = Bp0[(size_t)r * HD];
  __builtin_amdgcn_sched_barrier(0);
#pragma unroll
  for (int i = 0; i < 2; ++i) glds16(Abase[i], As0 + wv * 1024 + i * 512);
  __builtin_amdgcn_sched_barrier(0);
  {
    const TB* B1 = Bp0 + (size_t)64 * HD;
#pragma unroll
    for (int r = 0; r < 16; ++r) pB[r] = B1[(size_t)r * HD];
  }
  __builtin_amdgcn_sched_barrier(0);
#pragma unroll
  for (int i = 0; i < 2; ++i) glds16(Abase[i] + 64, As1 + wv * 1024 + i * 512);
  __builtin_amdgcn_sched_barrier(0);
  store_bx8(Bs[0], bcol, bkq * 32, pA);
  store_bx8(Bs[0], bcol, bkq * 32 + 16, pA + 8);
  asm volatile("s_waitcnt vmcnt(18) lgkmcnt(0)" ::: "memory");
  __builtin_amdgcn_s_barrier();
  __builtin_amdgcn_sched_barrier(0);

  f32x4 acc[2][4];
#pragma unroll
  for (int i = 0; i < 2; ++i)
#pragma unroll
    for (int j = 0; j < 4; ++j) acc[i][j] = (f32x4)(0.f);

  __bf16 *Ac = As0, *A1 = As1, *A2 = As2;
  for (int s = 0; s < 8; s += 2) {
    G2STEP(s,     Ac, A2, Bs[0], Bs[1], pA, pB);
    { __bf16* t = Ac; Ac = A1; A1 = A2; A2 = t; }
    G2STEP(s + 1, Ac, A2, Bs[1], Bs[0], pB, pA);
    { __bf16* t = Ac; Ac = A1; A1 = A2; A2 = t; }
  }
  // epilogue
#pragma unroll
  for (int mi = 0; mi < 2; ++mi) {
#pragma unroll
    for (int r = 0; r < 4; ++r) {
      int rl = wrow * 32 + mi * 16 + lq * 4 + r;
      if (rl < rows) {
        int gr = row0 + rl;
        float wgt = row_w[gr];
        if (MODE == 1) {
          __bf16* prow = (__bf16*)dstv + (size_t)gr * HD + n0 + wc * 64;
#pragma unroll
          for (int j = 0; j < 4; ++j)
            prow[j * 16 + l15] = (__bf16)(acc[mi][j][r] * wgt);
        } else {
          int tok = row_token[gr];
          float* orow = (float*)dstv + (size_t)tok * HD + n0 + wc * 64;
#pragma unroll
          for (int j = 0; j < 4; ++j)
            atomicAdd(&orow[j * 16 + l15], acc[mi][j][r] * wgt);
        }
      }
    }
  }
}

// ---------------- combine: out[t] = sum of 8 routed rows + shared row (bf16 in) --------
__global__ __launch_bounds__(256) void combine_kernel(const __bf16* __restrict__ pairout,
                                                      const int* __restrict__ inv8,
                                                      float* __restrict__ out) {
  int t = blockIdx.x;
  int c = threadIdx.x * 8;
  float s0 = 0.f, s1 = 0.f, s2 = 0.f, s3 = 0.f, s4 = 0.f, s5 = 0.f, s6 = 0.f, s7 = 0.f;
#pragma unroll
  for (int k = 0; k < 8; ++k) {
    bf16x8 v = *(const bf16x8*)(pairout + (size_t)inv8[t * 8 + k] * HD + c);
    s0 += (float)v[0]; s1 += (float)v[1]; s2 += (float)v[2]; s3 += (float)v[3];
    s4 += (float)v[4]; s5 += (float)v[5]; s6 += (float)v[6]; s7 += (float)v[7];
  }
  {
    bf16x8 v = *(const bf16x8*)(pairout + (size_t)(NPAIR + t) * HD + c);
    s0 += (float)v[0]; s1 += (float)v[1]; s2 += (float)v[2]; s3 += (float)v[3];
    s4 += (float)v[4]; s5 += (float)v[5]; s6 += (float)v[6]; s7 += (float)v[7];
  }
  float4* o = (float4*)(out + (size_t)t * HD + c);
  o[0] = float4{s0, s1, s2, s3};
  o[1] = float4{s4, s5, s6, s7};
}

// ---------------- launch ----------------
extern "C" void kernel_launch(void* const* d_in, const int* in_sizes, int n_in,
                              void* d_out, int out_size, void* d_ws, size_t ws_size,
                              hipStream_t stream) {
  const float* hidden = (const float*)d_in[0];
  const float* gate_w = (const float*)d_in[1];
  const float* w13    = (const float*)d_in[2];
  const float* w2     = (const float*)d_in[3];
  const float* sw13   = (const float*)d_in[4];
  const float* sw2    = (const float*)d_in[5];
  float* out = (float*)d_out;

  char* ws = (char*)d_ws;
  size_t off = 0;
  __bf16* hbuf      = (__bf16*)(ws + off); off += (size_t)NROWS * IMID * 2;
  __bf16* hidden_bf = (__bf16*)(ws + off); off += (size_t)T_TOK * HD * 2;
  float* logits  = (float*)(ws + off);  off += (size_t)T_TOK * NE * 4;
  int*   topk_id = (int*)(ws + off);    off += (size_t)NPAIR * 4;
  float* pair_w  = (float*)(ws + off);  off += (size_t)NPAIR * 4;
  int*   row_tok = (int*)(ws + off);    off += (size_t)NROWS * 4;
  float* row_w   = (float*)(ws + off);  off += (size_t)NROWS * 4;
  int*   inv8    = (int*)(ws + off);    off += (size_t)NPAIR * 4;
  int*   counts  = (int*)(ws + off);    off += 512;
  int*   curs    = (int*)(ws + off);    off += 512;
  int*   offs    = (int*)(ws + off);    off += 512;
  int2*  tiles   = (int2*)(ws + off);   off += MAXT1 * 8;
  off = (off + 255) & ~(size_t)255;
  __bf16* pairout = (__bf16*)(ws + off);
  size_t need_rows = off + (size_t)NROWS * HD * 2;     // +151 MB (bf16)
  bool rows_path = (ws_size >= need_rows);
  size_t woff = (need_rows + 255) & ~(size_t)255;
  __bf16* w2b = (__bf16*)(ws + woff);                  // w2 then sw2, contiguous bf16
  bool wfit = rows_path && (ws_size >= woff + (W2ELEMS + SW2ELEMS) * 2);  // +136 MB

  init_small<<<1, 256, 0, stream>>>(counts, curs);
  if (!rows_path)
    zero_out_kernel<<<T_TOK * HD / 4 / 256, 256, 0, stream>>>((float4*)out);
  logits_kernel<<<T_TOK / 16, 256, 0, stream>>>(hidden, gate_w, logits, hidden_bf);
  top8_kernel<<<T_TOK / 4, 256, 0, stream>>>(logits, topk_id, pair_w, counts);
  scan_kernel<<<1, 128, 0, stream>>>(counts, offs, tiles);
  scatter_kernel<<<NROWS / 256, 256, 0, stream>>>(topk_id, pair_w, offs, curs,
                                                  row_tok, row_w, inv8);
  if (wfit) {
    gemm1_kernel<1><<<dim3(8, MAXT1 + CVTY), 512, 0, stream>>>(
        hidden_bf, w13, sw13, row_tok, tiles, hbuf, w2, sw2, w2b);
    gemm2_kernel<__bf16, 1><<<dim3(16, MAXT1), 512, 0, stream>>>(
        hbuf, w2b, w2b + W2ELEMS, row_tok, row_w, tiles, (void*)pairout);
    combine_kernel<<<T_TOK, 256, 0, stream>>>(pairout, inv8, out);
  } else {
    gemm1_kernel<0><<<dim3(8, MAXT1), 512, 0, stream>>>(
        hidden_bf, w13, sw13, row_tok, tiles, hbuf, nullptr, nullptr, nullptr);
    if (rows_path) {
      gemm2_kernel<float, 1><<<dim3(16, MAXT1), 512, 0, stream>>>(
          hbuf, w2, sw2, row_tok, row_w, tiles, (void*)pairout);
      combine_kernel<<<T_TOK, 256, 0, stream>>>(pairout, inv8, out);
    } else {
      gemm2_kernel<float, 0><<<dim3(16, MAXT1), 512, 0, stream>>>(
          hbuf, w2, sw2, row_tok, row_w, tiles, (void*)out);
    }
  }
}

// Round 20
// 709.127 us; speedup vs baseline: 1.0615x; 1.0615x over previous
//
#include <hip/hip_runtime.h>
#include <hip/hip_bf16.h>

// ---------------- problem constants ----------------
#define T_TOK 4096
#define HD    2048
#define NE    64
#define TOPK  8
#define IMID  512
#define N13   1024                 // 2*I
#define NPAIR (T_TOK*TOPK)         // 32768
#define NROWS (NPAIR + T_TOK)      // 36864
#define MAXT1 352                  // 128-row tiles
#define RSCALE 2.5f

typedef __attribute__((ext_vector_type(8)))  __bf16 bf16x8;
typedef __attribute__((ext_vector_type(4)))  __bf16 bf16x4;
typedef __attribute__((ext_vector_type(4)))  float  f32x4;

// NOTE (hard-won): __launch_bounds__ 2nd arg on this hipcc = min BLOCKS/CU.
// (512,4) caps VGPR at 64 -> catastrophic spill (R13). Use (512,2) = 128 VGPRs.

// ---------------- init: counters only ----------------
__global__ void init_small(int* __restrict__ counts, int* __restrict__ curs) {
  int tid = threadIdx.x;
  if (tid < NE + 1) { counts[tid] = 0; curs[tid] = 0; }
}
__global__ __launch_bounds__(256) void zero_out_kernel(float4* __restrict__ out4) {
  out4[blockIdx.x * 256 + threadIdx.x] = float4{0.f, 0.f, 0.f, 0.f};
}

// ---------------- router logits (16 tokens/block) + fused hidden->bf16 ----------------
// Each block streams tokens [tb,tb+16) x full K exactly once -> also emits hidden_bf.
__global__ __launch_bounds__(256) void logits_kernel(const float* __restrict__ hs,
                                                     const float* __restrict__ gw,
                                                     float* __restrict__ logits,
                                                     __bf16* __restrict__ hidden_bf) {
  __shared__ float hsm[64][16];
  __shared__ float gwm[64][64];
  int tid = threadIdx.x;
  int tb = blockIdx.x * 16;
  int tok = tid >> 4, e4 = (tid & 15) * 4;
  float acc[4] = {0.f, 0.f, 0.f, 0.f};
  for (int c = 0; c < 32; ++c) {
    int kb = c * 64;
    {
      int t16 = tid & 15, kq = tid >> 4;
      float4 f = *(const float4*)&hs[(size_t)(tb + t16) * HD + kb + kq * 4];
      hsm[kq * 4 + 0][t16] = f.x; hsm[kq * 4 + 1][t16] = f.y;
      hsm[kq * 4 + 2][t16] = f.z; hsm[kq * 4 + 3][t16] = f.w;
      bf16x4 hv = { (__bf16)f.x, (__bf16)f.y, (__bf16)f.z, (__bf16)f.w };
      *(bf16x4*)&hidden_bf[(size_t)(tb + t16) * HD + kb + kq * 4] = hv;
#pragma unroll
      for (int it = 0; it < 4; ++it) {
        int q = tid + it * 256;
        int gr = q >> 4, gc = (q & 15) * 4;
        *(float4*)&gwm[gr][gc] = *(const float4*)&gw[(size_t)(kb + gr) * NE + gc];
      }
    }
    __syncthreads();
#pragma unroll 8
    for (int k = 0; k < 64; ++k) {
      float h = hsm[k][tok];
      float4 g = *(const float4*)&gwm[k][e4];
      acc[0] += h * g.x; acc[1] += h * g.y; acc[2] += h * g.z; acc[3] += h * g.w;
    }
    __syncthreads();
  }
#pragma unroll
  for (int j = 0; j < 4; ++j) logits[(size_t)(tb + tok) * NE + e4 + j] = acc[j];
}

// ---------------- sigmoid + top-8 ----------------
__global__ __launch_bounds__(256) void top8_kernel(const float* __restrict__ logits,
                                                   int* __restrict__ topk_id,
                                                   float* __restrict__ pair_w,
                                                   int* __restrict__ counts) {
  int lane = threadIdx.x & 63;
  int t = blockIdx.x * 4 + (threadIdx.x >> 6);
  float v = logits[(size_t)t * NE + lane];
  float s = 1.f / (1.f + __expf(-v));
  float cur = s, ssum = 0.f;
  int myid = 0; float myw = 0.f;
  for (int k = 0; k < TOPK; ++k) {
    float bv = cur; int bi = lane;
#pragma unroll
    for (int off = 32; off >= 1; off >>= 1) {
      float ov = __shfl_xor(bv, off);
      int   oi = __shfl_xor(bi, off);
      if (ov > bv || (ov == bv && oi < bi)) { bv = ov; bi = oi; }
    }
    ssum += bv;
    if (lane == k) { myid = bi; myw = bv; }
    if (lane == bi) cur = -1.f;
  }
  if (lane < TOPK) {
    topk_id[(size_t)t * TOPK + lane] = myid;
    pair_w[(size_t)t * TOPK + lane] = myw / ssum * RSCALE;
    atomicAdd(&counts[myid], 1);
  }
}

// ---------------- scan: LDS-resident, 128-row tiles ----------------
__global__ void scan_kernel(const int* __restrict__ counts, int* __restrict__ offs,
                            int2* __restrict__ tiles) {
  __shared__ int cnt[65], pref[66], tp[66];
  int tid = threadIdx.x;                     // 128 threads
  if (tid < 64) cnt[tid] = counts[tid];
  if (tid == 64) cnt[64] = T_TOK;
  __syncthreads();
  if (tid == 0) {
    int o = 0, t = 0;
    for (int e = 0; e <= 64; ++e) {
      pref[e] = o; tp[e] = t;
      o += cnt[e]; t += (cnt[e] + 127) >> 7;
    }
    pref[65] = o; tp[65] = t;
  }
  __syncthreads();
  if (tid <= 64) {
    offs[tid] = pref[tid];
    int c = cnt[tid], base = pref[tid], tb = tp[tid];
    int nt = (c + 127) >> 7;
    for (int i = 0; i < nt; ++i) {
      int rr = c - i * 128; if (rr > 128) rr = 128;
      tiles[tb + i] = make_int2(base + i * 128, (tid << 16) | rr);
    }
  }
  __syncthreads();
  for (int i = tp[65] + tid; i < MAXT1; i += 128) tiles[i] = make_int2(0, 0);
}

// ---------------- scatter (+ inverse map for combine) ----------------
__global__ __launch_bounds__(256) void scatter_kernel(const int* __restrict__ topk_id,
                                                      const float* __restrict__ pair_w,
                                                      const int* __restrict__ offs,
                                                      int* __restrict__ curs,
                                                      int* __restrict__ row_token,
                                                      float* __restrict__ row_w,
                                                      int* __restrict__ inv8) {
  int p = blockIdx.x * 256 + threadIdx.x;
  int dst, t; float w;
  if (p < NPAIR) {
    t = p >> 3; int e = topk_id[p]; w = pair_w[p];
    dst = offs[e] + atomicAdd(&curs[e], 1);
    inv8[p] = dst;
  } else {
    t = p - NPAIR; w = 1.0f;
    dst = NPAIR + t;
  }
  row_token[dst] = t;
  row_w[dst] = w;
}

// ---------------- helpers ----------------
__device__ __forceinline__ int swz(int row, int kbyte) {     // [row][64 bf16 = 128B]
  return row * 128 + (kbyte ^ ((row & 7) << 4));
}
__device__ __forceinline__ void glds16(const void* g, void* l) {
  __builtin_amdgcn_global_load_lds((const __attribute__((address_space(1))) void*)g,
                                   (__attribute__((address_space(3))) void*)l, 16, 0, 0);
}
// 8 fp32 -> one swizzled bf16x8 LDS write (conflict-proven one-col pattern)
__device__ __forceinline__ void store_bx8(__bf16* Bs, int col, int kbyte, const float* p) {
  bf16x8 v = { (__bf16)p[0], (__bf16)p[1], (__bf16)p[2], (__bf16)p[3],
               (__bf16)p[4], (__bf16)p[5], (__bf16)p[6], (__bf16)p[7] };
  *(bf16x8*)&Bs[swz(col, kbyte) >> 1] = v;
}

// ======= grouped GEMM1: 512 thr, BM=128, BN=64g+64u (nsplit 8), BK=64 ==================
// R11-proven: A glds depth-2 into THREE 16KB buffers; B reg depth-2 -> dbuf LDS.
// 80KB LDS -> 2 blocks/CU. Ledger: step s issues {B(s+2) x16, glds A(s+2) x2};
// bottom vmcnt(18) retires exactly glds(s); nothing issued this step is waited here.
#define G1STEP(S, Acur, Anx2, BGc, BUc, BGn, BUn, RL, RS)                                  \
  {                                                                                        \
    if ((S) + 2 < 32) {                                                                    \
      const float* Bn_ = Bp0 + (size_t)((S) + 2) * 64 * N13;                               \
      _Pragma("unroll") for (int r = 0; r < 16; ++r) RL[r] = Bn_[(size_t)r * N13];         \
      __builtin_amdgcn_sched_barrier(0);                                                   \
      _Pragma("unroll") for (int i = 0; i < 2; ++i)                                        \
        glds16(Abase[i] + ((S) + 2) * 64, (Anx2) + wv * 1024 + i * 512);                   \
    }                                                                                      \
    __builtin_amdgcn_sched_barrier(0);                                                     \
    __builtin_amdgcn_s_setprio(1);                                                         \
    _Pragma("unroll") for (int kk = 0; kk < 2; ++kk) {                                     \
      int koff = kk * 64 + lq * 16;                                                        \
      bf16x8 a[2], bg[2], bu[2];                                                           \
      _Pragma("unroll") for (int i = 0; i < 2; ++i)                                        \
        a[i] = *(const bf16x8*)&(Acur)[swz(wrow * 32 + i * 16 + l15, koff) >> 1];          \
      _Pragma("unroll") for (int j = 0; j < 2; ++j) {                                      \
        bg[j] = *(const bf16x8*)&(BGc)[swz(wc * 32 + j * 16 + l15, koff) >> 1];            \
        bu[j] = *(const bf16x8*)&(BUc)[swz(wc * 32 + j * 16 + l15, koff) >> 1];            \
      }                                                                                    \
      _Pragma("unroll") for (int i = 0; i < 2; ++i)                                        \
        _Pragma("unroll") for (int j = 0; j < 2; ++j) {                                    \
          accg[i][j] = __builtin_amdgcn_mfma_f32_16x16x32_bf16(a[i], bg[j], accg[i][j], 0, 0, 0); \
          accu[i][j] = __builtin_amdgcn_mfma_f32_16x16x32_bf16(a[i], bu[j], accu[i][j], 0, 0, 0); \
        }                                                                                  \
    }                                                                                      \
    __builtin_amdgcn_s_setprio(0);                                                         \
    if ((S) + 1 < 32) {                                                                    \
      __bf16* Bmy_ = bm ? (BUn) : (BGn);                                                   \
      store_bx8(Bmy_, bcol, bkq * 32, RS);                                                 \
      store_bx8(Bmy_, bcol, bkq * 32 + 16, RS + 8);                                        \
    }                                                                                      \
    if ((S) + 2 < 32) asm volatile("s_waitcnt vmcnt(18) lgkmcnt(0)" ::: "memory");         \
    else              asm volatile("s_waitcnt vmcnt(0) lgkmcnt(0)"  ::: "memory");         \
    __builtin_amdgcn_s_barrier();                                                          \
    __builtin_amdgcn_sched_barrier(0);                                                     \
  }

__global__ __launch_bounds__(512, 2) void gemm1_kernel(const __bf16* __restrict__ hidden_bf,
                                                       const float* __restrict__ w13,
                                                       const float* __restrict__ sw13,
                                                       const int* __restrict__ row_token,
                                                       const int2* __restrict__ tiles,
                                                       __bf16* __restrict__ hbuf) {
  int2 td = tiles[blockIdx.y];
  int rows = td.y & 0xFFFF;
  if (rows == 0) return;
  int e = td.y >> 16, row0 = td.x;
  const float* W = (e < NE) ? (w13 + (size_t)e * (HD * N13)) : sw13;  // [2048][1024]
  int n0 = blockIdx.x * 64;                                           // gate cols; up +512

  __shared__ __bf16 As0[128 * 64], As1[128 * 64], As2[128 * 64];  // 3 x 16 KB
  __shared__ __bf16 Bgs[2][64 * 64];                // 16 KB
  __shared__ __bf16 Bus[2][64 * 64];                // 16 KB   -> 80 KB total

  int tid = threadIdx.x;
  int lane = tid & 63, wv = tid >> 6;          // 8 waves
  int wrow = wv >> 1, wc = wv & 1;             // rows [wrow*32,+32), col-half wc
  int l15 = lane & 15, lq = lane >> 4;

  int kswz = (((lane & 7) ^ ((lane >> 3) & 7)) << 3);
  const __bf16* Abase[2];
#pragma unroll
  for (int i = 0; i < 2; ++i) {
    int grow = row0 + wv * 16 + i * 8 + (lane >> 3);
    if (grow >= NROWS) grow = NROWS - 1;
    Abase[i] = hidden_bf + (size_t)row_token[grow] * HD + kswz;
  }
  int bm = tid >> 8, bcol = tid & 63, bkq = (tid >> 6) & 3;
  const float* Bp0 = W + (size_t)(bkq * 16) * N13 + (bm ? 512 + n0 : n0) + bcol;

  // ---- prologue: B(0)->pA, glds A(0)->As0; B(1)->pB, glds A(1)->As1; store B(0) ----
  float pA[16], pB[16];
#pragma unroll
  for (int r = 0; r < 16; ++r) pA[r] = Bp0[(size_t)r * N13];
  __builtin_amdgcn_sched_barrier(0);
#pragma unroll
  for (int i = 0; i < 2; ++i) glds16(Abase[i], As0 + wv * 1024 + i * 512);
  __builtin_amdgcn_sched_barrier(0);
  {
    const float* B1 = Bp0 + (size_t)64 * N13;
#pragma unroll
    for (int r = 0; r < 16; ++r) pB[r] = B1[(size_t)r * N13];
  }
  __builtin_amdgcn_sched_barrier(0);
#pragma unroll
  for (int i = 0; i < 2; ++i) glds16(Abase[i] + 64, As1 + wv * 1024 + i * 512);
  __builtin_amdgcn_sched_barrier(0);
  {
    __bf16* Bmy = bm ? Bus[0] : Bgs[0];
    store_bx8(Bmy, bcol, bkq * 32, pA);
    store_bx8(Bmy, bcol, bkq * 32 + 16, pA + 8);
  }
  asm volatile("s_waitcnt vmcnt(18) lgkmcnt(0)" ::: "memory");   // retires glds(0)
  __builtin_amdgcn_s_barrier();
  __builtin_amdgcn_sched_barrier(0);

  f32x4 accg[2][2], accu[2][2];
#pragma unroll
  for (int i = 0; i < 2; ++i)
#pragma unroll
    for (int j = 0; j < 2; ++j) { accg[i][j] = (f32x4)(0.f); accu[i][j] = (f32x4)(0.f); }

  __bf16 *Ac = As0, *A1 = As1, *A2 = As2;
  for (int s = 0; s < 32; s += 2) {
    G1STEP(s,     Ac, A2, Bgs[0], Bus[0], Bgs[1], Bus[1], pA, pB);
    { __bf16* t = Ac; Ac = A1; A1 = A2; A2 = t; }
    G1STEP(s + 1, Ac, A2, Bgs[1], Bus[1], Bgs[0], Bus[0], pB, pA);
    { __bf16* t = Ac; Ac = A1; A1 = A2; A2 = t; }
  }
  // epilogue: h = silu(g)*u
#pragma unroll
  for (int mi = 0; mi < 2; ++mi) {
#pragma unroll
    for (int r = 0; r < 4; ++r) {
      int rl = wrow * 32 + mi * 16 + lq * 4 + r;
      if (rl < rows) {
        size_t hrow = (size_t)(row0 + rl) * IMID;
#pragma unroll
        for (int j = 0; j < 2; ++j) {
          float g = accg[mi][j][r], u = accu[mi][j][r];
          float hv = g * u / (1.f + __expf(-g));
          hbuf[hrow + n0 + wc * 32 + j * 16 + l15] = (__bf16)hv;
        }
      }
    }
  }
}

// ======= grouped GEMM2: 512 thr, BM=128, BN=128 (nsplit 16), BK=64 =====================
// Same R11 pipeline; MODE 1 writes bf16 weight-premultiplied rows.
#define G2STEP(S, Acur, Anx2, Bc, Bn, RL, RS)                                              \
  {                                                                                        \
    if ((S) + 2 < 8) {                                                                     \
      const float* Bn_ = Bp0 + (size_t)((S) + 2) * 64 * HD;                                \
      _Pragma("unroll") for (int r = 0; r < 16; ++r) RL[r] = Bn_[(size_t)r * HD];          \
      __builtin_amdgcn_sched_barrier(0);                                                   \
      _Pragma("unroll") for (int i = 0; i < 2; ++i)                                        \
        glds16(Abase[i] + ((S) + 2) * 64, (Anx2) + wv * 1024 + i * 512);                   \
    }                                                                                      \
    __builtin_amdgcn_sched_barrier(0);                                                     \
    __builtin_amdgcn_s_setprio(1);                                                         \
    _Pragma("unroll") for (int kk = 0; kk < 2; ++kk) {                                     \
      int koff = kk * 64 + lq * 16;                                                        \
      bf16x8 a[2], b[4];                                                                   \
      _Pragma("unroll") for (int i = 0; i < 2; ++i)                                        \
        a[i] = *(const bf16x8*)&(Acur)[swz(wrow * 32 + i * 16 + l15, koff) >> 1];          \
      _Pragma("unroll") for (int j = 0; j < 4; ++j)                                        \
        b[j] = *(const bf16x8*)&(Bc)[swz(wc * 64 + j * 16 + l15, koff) >> 1];              \
      _Pragma("unroll") for (int i = 0; i < 2; ++i)                                        \
        _Pragma("unroll") for (int j = 0; j < 4; ++j)                                      \
          acc[i][j] = __builtin_amdgcn_mfma_f32_16x16x32_bf16(a[i], b[j], acc[i][j], 0, 0, 0); \
    }                                                                                      \
    __builtin_amdgcn_s_setprio(0);                                                         \
    if ((S) + 1 < 8) {                                                                     \
      store_bx8((Bn), bcol, bkq * 32, RS);                                                 \
      store_bx8((Bn), bcol, bkq * 32 + 16, RS + 8);                                        \
    }                                                                                      \
    if ((S) + 2 < 8) asm volatile("s_waitcnt vmcnt(18) lgkmcnt(0)" ::: "memory");          \
    else             asm volatile("s_waitcnt vmcnt(0) lgkmcnt(0)"  ::: "memory");          \
    __builtin_amdgcn_s_barrier();                                                          \
    __builtin_amdgcn_sched_barrier(0);                                                     \
  }

template<int MODE>
__global__ __launch_bounds__(512, 2) void gemm2_kernel(const __bf16* __restrict__ hbuf,
                                                       const float* __restrict__ w2,
                                                       const float* __restrict__ sw2,
                                                       const int* __restrict__ row_token,
                                                       const float* __restrict__ row_w,
                                                       const int2* __restrict__ tiles,
                                                       void* __restrict__ dstv) {
  int2 td = tiles[blockIdx.y];
  int rows = td.y & 0xFFFF;
  if (rows == 0) return;
  int e = td.y >> 16, row0 = td.x;
  const float* W = (e < NE) ? (w2 + (size_t)e * (IMID * HD)) : sw2;   // [512][2048]
  int n0 = blockIdx.x * 128;

  __shared__ __bf16 As0[128 * 64], As1[128 * 64], As2[128 * 64];  // 3 x 16 KB
  __shared__ __bf16 Bs[2][128 * 64];                // 32 KB   -> 80 KB total

  int tid = threadIdx.x;
  int lane = tid & 63, wv = tid >> 6;
  int wrow = wv >> 1, wc = wv & 1;             // rows [wrow*32,+32), cols [wc*64,+64)
  int l15 = lane & 15, lq = lane >> 4;

  int kswz = (((lane & 7) ^ ((lane >> 3) & 7)) << 3);
  const __bf16* Abase[2];
#pragma unroll
  for (int i = 0; i < 2; ++i) {
    int grow = row0 + wv * 16 + i * 8 + (lane >> 3);
    if (grow >= NROWS) grow = NROWS - 1;
    Abase[i] = hbuf + (size_t)grow * IMID + kswz;
  }
  int bcol = tid & 127, bkq = tid >> 7;        // one col, 16 k-rows
  const float* Bp0 = W + (size_t)(bkq * 16) * HD + n0 + bcol;

  float pA[16], pB[16];
#pragma unroll
  for (int r = 0; r < 16; ++r) pA[r] = Bp0[(size_t)r * HD];
  __builtin_amdgcn_sched_barrier(0);
#pragma unroll
  for (int i = 0; i < 2; ++i) glds16(Abase[i], As0 + wv * 1024 + i * 512);
  __builtin_amdgcn_sched_barrier(0);
  {
    const float* B1 = Bp0 + (size_t)64 * HD;
#pragma unroll
    for (int r = 0; r < 16; ++r) pB[r] = B1[(size_t)r * HD];
  }
  __builtin_amdgcn_sched_barrier(0);
#pragma unroll
  for (int i = 0; i < 2; ++i) glds16(Abase[i] + 64, As1 + wv * 1024 + i * 512);
  __builtin_amdgcn_sched_barrier(0);
  store_bx8(Bs[0], bcol, bkq * 32, pA);
  store_bx8(Bs[0], bcol, bkq * 32 + 16, pA + 8);
  asm volatile("s_waitcnt vmcnt(18) lgkmcnt(0)" ::: "memory");
  __builtin_amdgcn_s_barrier();
  __builtin_amdgcn_sched_barrier(0);

  f32x4 acc[2][4];
#pragma unroll
  for (int i = 0; i < 2; ++i)
#pragma unroll
    for (int j = 0; j < 4; ++j) acc[i][j] = (f32x4)(0.f);

  __bf16 *Ac = As0, *A1 = As1, *A2 = As2;
  for (int s = 0; s < 8; s += 2) {
    G2STEP(s,     Ac, A2, Bs[0], Bs[1], pA, pB);
    { __bf16* t = Ac; Ac = A1; A1 = A2; A2 = t; }
    G2STEP(s + 1, Ac, A2, Bs[1], Bs[0], pB, pA);
    { __bf16* t = Ac; Ac = A1; A1 = A2; A2 = t; }
  }
  // epilogue
#pragma unroll
  for (int mi = 0; mi < 2; ++mi) {
#pragma unroll
    for (int r = 0; r < 4; ++r) {
      int rl = wrow * 32 + mi * 16 + lq * 4 + r;
      if (rl < rows) {
        int gr = row0 + rl;
        float wgt = row_w[gr];
        if (MODE == 1) {
          __bf16* prow = (__bf16*)dstv + (size_t)gr * HD + n0 + wc * 64;
#pragma unroll
          for (int j = 0; j < 4; ++j)
            prow[j * 16 + l15] = (__bf16)(acc[mi][j][r] * wgt);
        } else {
          int tok = row_token[gr];
          float* orow = (float*)dstv + (size_t)tok * HD + n0 + wc * 64;
#pragma unroll
          for (int j = 0; j < 4; ++j)
            atomicAdd(&orow[j * 16 + l15], acc[mi][j][r] * wgt);
        }
      }
    }
  }
}

// ---------------- combine: out[t] = sum of 8 routed rows + shared row (bf16 in) --------
__global__ __launch_bounds__(256) void combine_kernel(const __bf16* __restrict__ pairout,
                                                      const int* __restrict__ inv8,
                                                      float* __restrict__ out) {
  int t = blockIdx.x;
  int c = threadIdx.x * 8;
  float s0 = 0.f, s1 = 0.f, s2 = 0.f, s3 = 0.f, s4 = 0.f, s5 = 0.f, s6 = 0.f, s7 = 0.f;
#pragma unroll
  for (int k = 0; k < 8; ++k) {
    bf16x8 v = *(const bf16x8*)(pairout + (size_t)inv8[t * 8 + k] * HD + c);
    s0 += (float)v[0]; s1 += (float)v[1]; s2 += (float)v[2]; s3 += (float)v[3];
    s4 += (float)v[4]; s5 += (float)v[5]; s6 += (float)v[6]; s7 += (float)v[7];
  }
  {
    bf16x8 v = *(const bf16x8*)(pairout + (size_t)(NPAIR + t) * HD + c);
    s0 += (float)v[0]; s1 += (float)v[1]; s2 += (float)v[2]; s3 += (float)v[3];
    s4 += (float)v[4]; s5 += (float)v[5]; s6 += (float)v[6]; s7 += (float)v[7];
  }
  float4* o = (float4*)(out + (size_t)t * HD + c);
  o[0] = float4{s0, s1, s2, s3};
  o[1] = float4{s4, s5, s6, s7};
}

// ---------------- launch ----------------
extern "C" void kernel_launch(void* const* d_in, const int* in_sizes, int n_in,
                              void* d_out, int out_size, void* d_ws, size_t ws_size,
                              hipStream_t stream) {
  const float* hidden = (const float*)d_in[0];
  const float* gate_w = (const float*)d_in[1];
  const float* w13    = (const float*)d_in[2];
  const float* w2     = (const float*)d_in[3];
  const float* sw13   = (const float*)d_in[4];
  const float* sw2    = (const float*)d_in[5];
  float* out = (float*)d_out;

  char* ws = (char*)d_ws;
  size_t off = 0;
  __bf16* hbuf      = (__bf16*)(ws + off); off += (size_t)NROWS * IMID * 2;
  __bf16* hidden_bf = (__bf16*)(ws + off); off += (size_t)T_TOK * HD * 2;
  float* logits  = (float*)(ws + off);  off += (size_t)T_TOK * NE * 4;
  int*   topk_id = (int*)(ws + off);    off += (size_t)NPAIR * 4;
  float* pair_w  = (float*)(ws + off);  off += (size_t)NPAIR * 4;
  int*   row_tok = (int*)(ws + off);    off += (size_t)NROWS * 4;
  float* row_w   = (float*)(ws + off);  off += (size_t)NROWS * 4;
  int*   inv8    = (int*)(ws + off);    off += (size_t)NPAIR * 4;
  int*   counts  = (int*)(ws + off);    off += 512;
  int*   curs    = (int*)(ws + off);    off += 512;
  int*   offs    = (int*)(ws + off);    off += 512;
  int2*  tiles   = (int2*)(ws + off);   off += MAXT1 * 8;
  off = (off + 255) & ~(size_t)255;
  __bf16* pairout = (__bf16*)(ws + off);
  size_t need_rows = off + (size_t)NROWS * HD * 2;     // +151 MB (bf16)
  bool rows_path = (ws_size >= need_rows);

  init_small<<<1, 256, 0, stream>>>(counts, curs);
  if (!rows_path)
    zero_out_kernel<<<T_TOK * HD / 4 / 256, 256, 0, stream>>>((float4*)out);
  logits_kernel<<<T_TOK / 16, 256, 0, stream>>>(hidden, gate_w, logits, hidden_bf);
  top8_kernel<<<T_TOK / 4, 256, 0, stream>>>(logits, topk_id, pair_w, counts);
  scan_kernel<<<1, 128, 0, stream>>>(counts, offs, tiles);
  scatter_kernel<<<NROWS / 256, 256, 0, stream>>>(topk_id, pair_w, offs, curs,
                                                  row_tok, row_w, inv8);
  gemm1_kernel<<<dim3(8, MAXT1), 512, 0, stream>>>(hidden_bf, w13, sw13, row_tok, tiles, hbuf);
  if (rows_path) {
    gemm2_kernel<1><<<dim3(16, MAXT1), 512, 0, stream>>>(hbuf, w2, sw2, row_tok, row_w,
                                                         tiles, (void*)pairout);
    combine_kernel<<<T_TOK, 256, 0, stream>>>(pairout, inv8, out);
  } else {
    gemm2_kernel<0><<<dim3(16, MAXT1), 512, 0, stream>>>(hbuf, w2, sw2, row_tok, row_w,
                                                         tiles, (void*)out);
  }
}

// Round 21
// 708.439 us; speedup vs baseline: 1.0626x; 1.0010x over previous
//
#include <hip/hip_runtime.h>
#include <hip/hip_bf16.h>

// ---------------- problem constants ----------------
#define T_TOK 4096
#define HD    2048
#define NE    64
#define TOPK  8
#define IMID  512
#define N13   1024                 // 2*I
#define NPAIR (T_TOK*TOPK)         // 32768
#define NROWS (NPAIR + T_TOK)      // 36864
#define MAXT1 352                  // 128-row tiles
#define RSCALE 2.5f

typedef __attribute__((ext_vector_type(8)))  __bf16 bf16x8;
typedef __attribute__((ext_vector_type(4)))  __bf16 bf16x4;
typedef __attribute__((ext_vector_type(4)))  float  f32x4;

// NOTE (hard-won): __launch_bounds__ 2nd arg on this hipcc = min BLOCKS/CU.
// (512,4) caps VGPR at 64 -> catastrophic spill (R13). Use (512,2) = 128 VGPRs.

// ---------------- init: counters only ----------------
__global__ void init_small(int* __restrict__ counts, int* __restrict__ curs) {
  int tid = threadIdx.x;
  if (tid < NE + 1) { counts[tid] = 0; curs[tid] = 0; }
}
__global__ __launch_bounds__(256) void zero_out_kernel(float4* __restrict__ out4) {
  out4[blockIdx.x * 256 + threadIdx.x] = float4{0.f, 0.f, 0.f, 0.f};
}

// ---------------- router logits (16 tokens/block) + fused hidden->bf16 ----------------
// Each block streams tokens [tb,tb+16) x full K exactly once -> also emits hidden_bf.
__global__ __launch_bounds__(256) void logits_kernel(const float* __restrict__ hs,
                                                     const float* __restrict__ gw,
                                                     float* __restrict__ logits,
                                                     __bf16* __restrict__ hidden_bf) {
  __shared__ float hsm[64][16];
  __shared__ float gwm[64][64];
  int tid = threadIdx.x;
  int tb = blockIdx.x * 16;
  int tok = tid >> 4, e4 = (tid & 15) * 4;
  float acc[4] = {0.f, 0.f, 0.f, 0.f};
  for (int c = 0; c < 32; ++c) {
    int kb = c * 64;
    {
      int t16 = tid & 15, kq = tid >> 4;
      float4 f = *(const float4*)&hs[(size_t)(tb + t16) * HD + kb + kq * 4];
      hsm[kq * 4 + 0][t16] = f.x; hsm[kq * 4 + 1][t16] = f.y;
      hsm[kq * 4 + 2][t16] = f.z; hsm[kq * 4 + 3][t16] = f.w;
      bf16x4 hv = { (__bf16)f.x, (__bf16)f.y, (__bf16)f.z, (__bf16)f.w };
      *(bf16x4*)&hidden_bf[(size_t)(tb + t16) * HD + kb + kq * 4] = hv;
#pragma unroll
      for (int it = 0; it < 4; ++it) {
        int q = tid + it * 256;
        int gr = q >> 4, gc = (q & 15) * 4;
        *(float4*)&gwm[gr][gc] = *(const float4*)&gw[(size_t)(kb + gr) * NE + gc];
      }
    }
    __syncthreads();
#pragma unroll 8
    for (int k = 0; k < 64; ++k) {
      float h = hsm[k][tok];
      float4 g = *(const float4*)&gwm[k][e4];
      acc[0] += h * g.x; acc[1] += h * g.y; acc[2] += h * g.z; acc[3] += h * g.w;
    }
    __syncthreads();
  }
#pragma unroll
  for (int j = 0; j < 4; ++j) logits[(size_t)(tb + tok) * NE + e4 + j] = acc[j];
}

// ---------------- sigmoid + top-8 ----------------
__global__ __launch_bounds__(256) void top8_kernel(const float* __restrict__ logits,
                                                   int* __restrict__ topk_id,
                                                   float* __restrict__ pair_w,
                                                   int* __restrict__ counts) {
  int lane = threadIdx.x & 63;
  int t = blockIdx.x * 4 + (threadIdx.x >> 6);
  float v = logits[(size_t)t * NE + lane];
  float s = 1.f / (1.f + __expf(-v));
  float cur = s, ssum = 0.f;
  int myid = 0; float myw = 0.f;
  for (int k = 0; k < TOPK; ++k) {
    float bv = cur; int bi = lane;
#pragma unroll
    for (int off = 32; off >= 1; off >>= 1) {
      float ov = __shfl_xor(bv, off);
      int   oi = __shfl_xor(bi, off);
      if (ov > bv || (ov == bv && oi < bi)) { bv = ov; bi = oi; }
    }
    ssum += bv;
    if (lane == k) { myid = bi; myw = bv; }
    if (lane == bi) cur = -1.f;
  }
  if (lane < TOPK) {
    topk_id[(size_t)t * TOPK + lane] = myid;
    pair_w[(size_t)t * TOPK + lane] = myw / ssum * RSCALE;
    atomicAdd(&counts[myid], 1);
  }
}

// ---------------- scan: LDS-resident, 128-row tiles ----------------
__global__ void scan_kernel(const int* __restrict__ counts, int* __restrict__ offs,
                            int2* __restrict__ tiles) {
  __shared__ int cnt[65], pref[66], tp[66];
  int tid = threadIdx.x;                     // 128 threads
  if (tid < 64) cnt[tid] = counts[tid];
  if (tid == 64) cnt[64] = T_TOK;
  __syncthreads();
  if (tid == 0) {
    int o = 0, t = 0;
    for (int e = 0; e <= 64; ++e) {
      pref[e] = o; tp[e] = t;
      o += cnt[e]; t += (cnt[e] + 127) >> 7;
    }
    pref[65] = o; tp[65] = t;
  }
  __syncthreads();
  if (tid <= 64) {
    offs[tid] = pref[tid];
    int c = cnt[tid], base = pref[tid], tb = tp[tid];
    int nt = (c + 127) >> 7;
    for (int i = 0; i < nt; ++i) {
      int rr = c - i * 128; if (rr > 128) rr = 128;
      tiles[tb + i] = make_int2(base + i * 128, (tid << 16) | rr);
    }
  }
  __syncthreads();
  for (int i = tp[65] + tid; i < MAXT1; i += 128) tiles[i] = make_int2(0, 0);
}

// ---------------- scatter (+ inverse map for combine) ----------------
__global__ __launch_bounds__(256) void scatter_kernel(const int* __restrict__ topk_id,
                                                      const float* __restrict__ pair_w,
                                                      const int* __restrict__ offs,
                                                      int* __restrict__ curs,
                                                      int* __restrict__ row_token,
                                                      float* __restrict__ row_w,
                                                      int* __restrict__ inv8) {
  int p = blockIdx.x * 256 + threadIdx.x;
  int dst, t; float w;
  if (p < NPAIR) {
    t = p >> 3; int e = topk_id[p]; w = pair_w[p];
    dst = offs[e] + atomicAdd(&curs[e], 1);
    inv8[p] = dst;
  } else {
    t = p - NPAIR; w = 1.0f;
    dst = NPAIR + t;
  }
  row_token[dst] = t;
  row_w[dst] = w;
}

// ---------------- helpers ----------------
__device__ __forceinline__ int swz(int row, int kbyte) {     // [row][64 bf16 = 128B]
  return row * 128 + (kbyte ^ ((row & 7) << 4));
}
__device__ __forceinline__ void glds16(const void* g, void* l) {
  __builtin_amdgcn_global_load_lds((const __attribute__((address_space(1))) void*)g,
                                   (__attribute__((address_space(3))) void*)l, 16, 0, 0);
}
// 8 fp32 -> one swizzled bf16x8 LDS write (conflict-proven one-col pattern)
__device__ __forceinline__ void store_bx8(__bf16* Bs, int col, int kbyte, const float* p) {
  bf16x8 v = { (__bf16)p[0], (__bf16)p[1], (__bf16)p[2], (__bf16)p[3],
               (__bf16)p[4], (__bf16)p[5], (__bf16)p[6], (__bf16)p[7] };
  *(bf16x8*)&Bs[swz(col, kbyte) >> 1] = v;
}

// ======= grouped GEMM1: 512 thr, BM=128, BN=64g+64u (nsplit 8), BK=64 ==================
// R11-proven: A glds depth-2 into THREE 16KB buffers; B reg depth-2 -> dbuf LDS.
// 80KB LDS -> 2 blocks/CU. Ledger: step s issues {B(s+2) x16, glds A(s+2) x2};
// bottom vmcnt(18) retires exactly glds(s); nothing issued this step is waited here.
#define G1STEP(S, Acur, Anx2, BGc, BUc, BGn, BUn, RL, RS)                                  \
  {                                                                                        \
    if ((S) + 2 < 32) {                                                                    \
      const float* Bn_ = Bp0 + (size_t)((S) + 2) * 64 * N13;                               \
      _Pragma("unroll") for (int r = 0; r < 16; ++r) RL[r] = Bn_[(size_t)r * N13];         \
      __builtin_amdgcn_sched_barrier(0);                                                   \
      _Pragma("unroll") for (int i = 0; i < 2; ++i)                                        \
        glds16(Abase[i] + ((S) + 2) * 64, (Anx2) + wv * 1024 + i * 512);                   \
    }                                                                                      \
    __builtin_amdgcn_sched_barrier(0);                                                     \
    __builtin_amdgcn_s_setprio(1);                                                         \
    _Pragma("unroll") for (int kk = 0; kk < 2; ++kk) {                                     \
      int koff = kk * 64 + lq * 16;                                                        \
      bf16x8 a[2], bg[2], bu[2];                                                           \
      _Pragma("unroll") for (int i = 0; i < 2; ++i)                                        \
        a[i] = *(const bf16x8*)&(Acur)[swz(wrow * 32 + i * 16 + l15, koff) >> 1];          \
      _Pragma("unroll") for (int j = 0; j < 2; ++j) {                                      \
        bg[j] = *(const bf16x8*)&(BGc)[swz(wc * 32 + j * 16 + l15, koff) >> 1];            \
        bu[j] = *(const bf16x8*)&(BUc)[swz(wc * 32 + j * 16 + l15, koff) >> 1];            \
      }                                                                                    \
      _Pragma("unroll") for (int i = 0; i < 2; ++i)                                        \
        _Pragma("unroll") for (int j = 0; j < 2; ++j) {                                    \
          accg[i][j] = __builtin_amdgcn_mfma_f32_16x16x32_bf16(a[i], bg[j], accg[i][j], 0, 0, 0); \
          accu[i][j] = __builtin_amdgcn_mfma_f32_16x16x32_bf16(a[i], bu[j], accu[i][j], 0, 0, 0); \
        }                                                                                  \
    }                                                                                      \
    __builtin_amdgcn_s_setprio(0);                                                         \
    if ((S) + 1 < 32) {                                                                    \
      __bf16* Bmy_ = bm ? (BUn) : (BGn);                                                   \
      store_bx8(Bmy_, bcol, bkq * 32, RS);                                                 \
      store_bx8(Bmy_, bcol, bkq * 32 + 16, RS + 8);                                        \
    }                                                                                      \
    if ((S) + 2 < 32) asm volatile("s_waitcnt vmcnt(18) lgkmcnt(0)" ::: "memory");         \
    else              asm volatile("s_waitcnt vmcnt(0) lgkmcnt(0)"  ::: "memory");         \
    __builtin_amdgcn_s_barrier();                                                          \
    __builtin_amdgcn_sched_barrier(0);                                                     \
  }

__global__ __launch_bounds__(512, 2) void gemm1_kernel(const __bf16* __restrict__ hidden_bf,
                                                       const float* __restrict__ w13,
                                                       const float* __restrict__ sw13,
                                                       const int* __restrict__ row_token,
                                                       const int2* __restrict__ tiles,
                                                       __bf16* __restrict__ hbuf) {
  int2 td = tiles[blockIdx.y];
  int rows = td.y & 0xFFFF;
  if (rows == 0) return;
  int e = td.y >> 16, row0 = td.x;
  const float* W = (e < NE) ? (w13 + (size_t)e * (HD * N13)) : sw13;  // [2048][1024]
  int n0 = blockIdx.x * 64;                                           // gate cols; up +512

  __shared__ __bf16 As0[128 * 64], As1[128 * 64], As2[128 * 64];  // 3 x 16 KB
  __shared__ __bf16 Bgs[2][64 * 64];                // 16 KB
  __shared__ __bf16 Bus[2][64 * 64];                // 16 KB   -> 80 KB total

  int tid = threadIdx.x;
  int lane = tid & 63, wv = tid >> 6;          // 8 waves
  int wrow = wv >> 1, wc = wv & 1;             // rows [wrow*32,+32), col-half wc
  int l15 = lane & 15, lq = lane >> 4;

  int kswz = (((lane & 7) ^ ((lane >> 3) & 7)) << 3);
  const __bf16* Abase[2];
#pragma unroll
  for (int i = 0; i < 2; ++i) {
    int grow = row0 + wv * 16 + i * 8 + (lane >> 3);
    if (grow >= NROWS) grow = NROWS - 1;
    Abase[i] = hidden_bf + (size_t)row_token[grow] * HD + kswz;
  }
  int bm = tid >> 8, bcol = tid & 63, bkq = (tid >> 6) & 3;
  const float* Bp0 = W + (size_t)(bkq * 16) * N13 + (bm ? 512 + n0 : n0) + bcol;

  // ---- prologue: B(0)->pA, glds A(0)->As0; B(1)->pB, glds A(1)->As1; store B(0) ----
  float pA[16], pB[16];
#pragma unroll
  for (int r = 0; r < 16; ++r) pA[r] = Bp0[(size_t)r * N13];
  __builtin_amdgcn_sched_barrier(0);
#pragma unroll
  for (int i = 0; i < 2; ++i) glds16(Abase[i], As0 + wv * 1024 + i * 512);
  __builtin_amdgcn_sched_barrier(0);
  {
    const float* B1 = Bp0 + (size_t)64 * N13;
#pragma unroll
    for (int r = 0; r < 16; ++r) pB[r] = B1[(size_t)r * N13];
  }
  __builtin_amdgcn_sched_barrier(0);
#pragma unroll
  for (int i = 0; i < 2; ++i) glds16(Abase[i] + 64, As1 + wv * 1024 + i * 512);
  __builtin_amdgcn_sched_barrier(0);
  {
    __bf16* Bmy = bm ? Bus[0] : Bgs[0];
    store_bx8(Bmy, bcol, bkq * 32, pA);
    store_bx8(Bmy, bcol, bkq * 32 + 16, pA + 8);
  }
  asm volatile("s_waitcnt vmcnt(18) lgkmcnt(0)" ::: "memory");   // retires glds(0)
  __builtin_amdgcn_s_barrier();
  __builtin_amdgcn_sched_barrier(0);

  f32x4 accg[2][2], accu[2][2];
#pragma unroll
  for (int i = 0; i < 2; ++i)
#pragma unroll
    for (int j = 0; j < 2; ++j) { accg[i][j] = (f32x4)(0.f); accu[i][j] = (f32x4)(0.f); }

  __bf16 *Ac = As0, *A1 = As1, *A2 = As2;
  for (int s = 0; s < 32; s += 2) {
    G1STEP(s,     Ac, A2, Bgs[0], Bus[0], Bgs[1], Bus[1], pA, pB);
    { __bf16* t = Ac; Ac = A1; A1 = A2; A2 = t; }
    G1STEP(s + 1, Ac, A2, Bgs[1], Bus[1], Bgs[0], Bus[0], pB, pA);
    { __bf16* t = Ac; Ac = A1; A1 = A2; A2 = t; }
  }
  // epilogue: h = silu(g)*u
#pragma unroll
  for (int mi = 0; mi < 2; ++mi) {
#pragma unroll
    for (int r = 0; r < 4; ++r) {
      int rl = wrow * 32 + mi * 16 + lq * 4 + r;
      if (rl < rows) {
        size_t hrow = (size_t)(row0 + rl) * IMID;
#pragma unroll
        for (int j = 0; j < 2; ++j) {
          float g = accg[mi][j][r], u = accu[mi][j][r];
          float hv = g * u / (1.f + __expf(-g));
          hbuf[hrow + n0 + wc * 32 + j * 16 + l15] = (__bf16)hv;
        }
      }
    }
  }
}

// ======= grouped GEMM2: 512 thr, BM=128, BN=128 (nsplit 16), BK=64 =====================
// Same R11 pipeline; MODE 1 writes bf16 weight-premultiplied rows.
#define G2STEP(S, Acur, Anx2, Bc, Bn, RL, RS)                                              \
  {                                                                                        \
    if ((S) + 2 < 8) {                                                                     \
      const float* Bn_ = Bp0 + (size_t)((S) + 2) * 64 * HD;                                \
      _Pragma("unroll") for (int r = 0; r < 16; ++r) RL[r] = Bn_[(size_t)r * HD];          \
      __builtin_amdgcn_sched_barrier(0);                                                   \
      _Pragma("unroll") for (int i = 0; i < 2; ++i)                                        \
        glds16(Abase[i] + ((S) + 2) * 64, (Anx2) + wv * 1024 + i * 512);                   \
    }                                                                                      \
    __builtin_amdgcn_sched_barrier(0);                                                     \
    __builtin_amdgcn_s_setprio(1);                                                         \
    _Pragma("unroll") for (int kk = 0; kk < 2; ++kk) {                                     \
      int koff = kk * 64 + lq * 16;                                                        \
      bf16x8 a[2], b[4];                                                                   \
      _Pragma("unroll") for (int i = 0; i < 2; ++i)                                        \
        a[i] = *(const bf16x8*)&(Acur)[swz(wrow * 32 + i * 16 + l15, koff) >> 1];          \
      _Pragma("unroll") for (int j = 0; j < 4; ++j)                                        \
        b[j] = *(const bf16x8*)&(Bc)[swz(wc * 64 + j * 16 + l15, koff) >> 1];              \
      _Pragma("unroll") for (int i = 0; i < 2; ++i)                                        \
        _Pragma("unroll") for (int j = 0; j < 4; ++j)                                      \
          acc[i][j] = __builtin_amdgcn_mfma_f32_16x16x32_bf16(a[i], b[j], acc[i][j], 0, 0, 0); \
    }                                                                                      \
    __builtin_amdgcn_s_setprio(0);                                                         \
    if ((S) + 1 < 8) {                                                                     \
      store_bx8((Bn), bcol, bkq * 32, RS);                                                 \
      store_bx8((Bn), bcol, bkq * 32 + 16, RS + 8);                                        \
    }                                                                                      \
    if ((S) + 2 < 8) asm volatile("s_waitcnt vmcnt(18) lgkmcnt(0)" ::: "memory");          \
    else             asm volatile("s_waitcnt vmcnt(0) lgkmcnt(0)"  ::: "memory");          \
    __builtin_amdgcn_s_barrier();                                                          \
    __builtin_amdgcn_sched_barrier(0);                                                     \
  }

template<int MODE>
__global__ __launch_bounds__(512, 2) void gemm2_kernel(const __bf16* __restrict__ hbuf,
                                                       const float* __restrict__ w2,
                                                       const float* __restrict__ sw2,
                                                       const int* __restrict__ row_token,
                                                       const float* __restrict__ row_w,
                                                       const int2* __restrict__ tiles,
                                                       void* __restrict__ dstv) {
  int2 td = tiles[blockIdx.y];
  int rows = td.y & 0xFFFF;
  if (rows == 0) return;
  int e = td.y >> 16, row0 = td.x;
  const float* W = (e < NE) ? (w2 + (size_t)e * (IMID * HD)) : sw2;   // [512][2048]
  int n0 = blockIdx.x * 128;

  __shared__ __bf16 As0[128 * 64], As1[128 * 64], As2[128 * 64];  // 3 x 16 KB
  __shared__ __bf16 Bs[2][128 * 64];                // 32 KB   -> 80 KB total

  int tid = threadIdx.x;
  int lane = tid & 63, wv = tid >> 6;
  int wrow = wv >> 1, wc = wv & 1;             // rows [wrow*32,+32), cols [wc*64,+64)
  int l15 = lane & 15, lq = lane >> 4;

  int kswz = (((lane & 7) ^ ((lane >> 3) & 7)) << 3);
  const __bf16* Abase[2];
#pragma unroll
  for (int i = 0; i < 2; ++i) {
    int grow = row0 + wv * 16 + i * 8 + (lane >> 3);
    if (grow >= NROWS) grow = NROWS - 1;
    Abase[i] = hbuf + (size_t)grow * IMID + kswz;
  }
  int bcol = tid & 127, bkq = tid >> 7;        // one col, 16 k-rows
  const float* Bp0 = W + (size_t)(bkq * 16) * HD + n0 + bcol;

  float pA[16], pB[16];
#pragma unroll
  for (int r = 0; r < 16; ++r) pA[r] = Bp0[(size_t)r * HD];
  __builtin_amdgcn_sched_barrier(0);
#pragma unroll
  for (int i = 0; i < 2; ++i) glds16(Abase[i], As0 + wv * 1024 + i * 512);
  __builtin_amdgcn_sched_barrier(0);
  {
    const float* B1 = Bp0 + (size_t)64 * HD;
#pragma unroll
    for (int r = 0; r < 16; ++r) pB[r] = B1[(size_t)r * HD];
  }
  __builtin_amdgcn_sched_barrier(0);
#pragma unroll
  for (int i = 0; i < 2; ++i) glds16(Abase[i] + 64, As1 + wv * 1024 + i * 512);
  __builtin_amdgcn_sched_barrier(0);
  store_bx8(Bs[0], bcol, bkq * 32, pA);
  store_bx8(Bs[0], bcol, bkq * 32 + 16, pA + 8);
  asm volatile("s_waitcnt vmcnt(18) lgkmcnt(0)" ::: "memory");
  __builtin_amdgcn_s_barrier();
  __builtin_amdgcn_sched_barrier(0);

  f32x4 acc[2][4];
#pragma unroll
  for (int i = 0; i < 2; ++i)
#pragma unroll
    for (int j = 0; j < 4; ++j) acc[i][j] = (f32x4)(0.f);

  __bf16 *Ac = As0, *A1 = As1, *A2 = As2;
  for (int s = 0; s < 8; s += 2) {
    G2STEP(s,     Ac, A2, Bs[0], Bs[1], pA, pB);
    { __bf16* t = Ac; Ac = A1; A1 = A2; A2 = t; }
    G2STEP(s + 1, Ac, A2, Bs[1], Bs[0], pB, pA);
    { __bf16* t = Ac; Ac = A1; A1 = A2; A2 = t; }
  }
  // epilogue
#pragma unroll
  for (int mi = 0; mi < 2; ++mi) {
#pragma unroll
    for (int r = 0; r < 4; ++r) {
      int rl = wrow * 32 + mi * 16 + lq * 4 + r;
      if (rl < rows) {
        int gr = row0 + rl;
        float wgt = row_w[gr];
        if (MODE == 1) {
          __bf16* prow = (__bf16*)dstv + (size_t)gr * HD + n0 + wc * 64;
#pragma unroll
          for (int j = 0; j < 4; ++j)
            prow[j * 16 + l15] = (__bf16)(acc[mi][j][r] * wgt);
        } else {
          int tok = row_token[gr];
          float* orow = (float*)dstv + (size_t)tok * HD + n0 + wc * 64;
#pragma unroll
          for (int j = 0; j < 4; ++j)
            atomicAdd(&orow[j * 16 + l15], acc[mi][j][r] * wgt);
        }
      }
    }
  }
}

// ---------------- combine: out[t] = sum of 8 routed rows + shared row (bf16 in) --------
__global__ __launch_bounds__(256) void combine_kernel(const __bf16* __restrict__ pairout,
                                                      const int* __restrict__ inv8,
                                                      float* __restrict__ out) {
  int t = blockIdx.x;
  int c = threadIdx.x * 8;
  float s0 = 0.f, s1 = 0.f, s2 = 0.f, s3 = 0.f, s4 = 0.f, s5 = 0.f, s6 = 0.f, s7 = 0.f;
#pragma unroll
  for (int k = 0; k < 8; ++k) {
    bf16x8 v = *(const bf16x8*)(pairout + (size_t)inv8[t * 8 + k] * HD + c);
    s0 += (float)v[0]; s1 += (float)v[1]; s2 += (float)v[2]; s3 += (float)v[3];
    s4 += (float)v[4]; s5 += (float)v[5]; s6 += (float)v[6]; s7 += (float)v[7];
  }
  {
    bf16x8 v = *(const bf16x8*)(pairout + (size_t)(NPAIR + t) * HD + c);
    s0 += (float)v[0]; s1 += (float)v[1]; s2 += (float)v[2]; s3 += (float)v[3];
    s4 += (float)v[4]; s5 += (float)v[5]; s6 += (float)v[6]; s7 += (float)v[7];
  }
  float4* o = (float4*)(out + (size_t)t * HD + c);
  o[0] = float4{s0, s1, s2, s3};
  o[1] = float4{s4, s5, s6, s7};
}

// ---------------- launch ----------------
extern "C" void kernel_launch(void* const* d_in, const int* in_sizes, int n_in,
                              void* d_out, int out_size, void* d_ws, size_t ws_size,
                              hipStream_t stream) {
  const float* hidden = (const float*)d_in[0];
  const float* gate_w = (const float*)d_in[1];
  const float* w13    = (const float*)d_in[2];
  const float* w2     = (const float*)d_in[3];
  const float* sw13   = (const float*)d_in[4];
  const float* sw2    = (const float*)d_in[5];
  float* out = (float*)d_out;

  char* ws = (char*)d_ws;
  size_t off = 0;
  __bf16* hbuf      = (__bf16*)(ws + off); off += (size_t)NROWS * IMID * 2;
  __bf16* hidden_bf = (__bf16*)(ws + off); off += (size_t)T_TOK * HD * 2;
  float* logits  = (float*)(ws + off);  off += (size_t)T_TOK * NE * 4;
  int*   topk_id = (int*)(ws + off);    off += (size_t)NPAIR * 4;
  float* pair_w  = (float*)(ws + off);  off += (size_t)NPAIR * 4;
  int*   row_tok = (int*)(ws + off);    off += (size_t)NROWS * 4;
  float* row_w   = (float*)(ws + off);  off += (size_t)NROWS * 4;
  int*   inv8    = (int*)(ws + off);    off += (size_t)NPAIR * 4;
  int*   counts  = (int*)(ws + off);    off += 512;
  int*   curs    = (int*)(ws + off);    off += 512;
  int*   offs    = (int*)(ws + off);    off += 512;
  int2*  tiles   = (int2*)(ws + off);   off += MAXT1 * 8;
  off = (off + 255) & ~(size_t)255;
  __bf16* pairout = (__bf16*)(ws + off);
  size_t need_rows = off + (size_t)NROWS * HD * 2;     // +151 MB (bf16)
  bool rows_path = (ws_size >= need_rows);

  init_small<<<1, 256, 0, stream>>>(counts, curs);
  if (!rows_path)
    zero_out_kernel<<<T_TOK * HD / 4 / 256, 256, 0, stream>>>((float4*)out);
  logits_kernel<<<T_TOK / 16, 256, 0, stream>>>(hidden, gate_w, logits, hidden_bf);
  top8_kernel<<<T_TOK / 4, 256, 0, stream>>>(logits, topk_id, pair_w, counts);
  scan_kernel<<<1, 128, 0, stream>>>(counts, offs, tiles);
  scatter_kernel<<<NROWS / 256, 256, 0, stream>>>(topk_id, pair_w, offs, curs,
                                                  row_tok, row_w, inv8);
  gemm1_kernel<<<dim3(8, MAXT1), 512, 0, stream>>>(hidden_bf, w13, sw13, row_tok, tiles, hbuf);
  if (rows_path) {
    gemm2_kernel<1><<<dim3(16, MAXT1), 512, 0, stream>>>(hbuf, w2, sw2, row_tok, row_w,
                                                         tiles, (void*)pairout);
    combine_kernel<<<T_TOK, 256, 0, stream>>>(pairout, inv8, out);
  } else {
    gemm2_kernel<0><<<dim3(16, MAXT1), 512, 0, stream>>>(hbuf, w2, sw2, row_tok, row_w,
                                                         tiles, (void*)out);
  }
}